// Round 1
// baseline (95.111 us; speedup 1.0000x reference)
//
#include <hip/hip_runtime.h>

typedef _Float16 h8 __attribute__((ext_vector_type(8)));
typedef _Float16 h4 __attribute__((ext_vector_type(4)));
typedef _Float16 h2 __attribute__((ext_vector_type(2)));
typedef float f4 __attribute__((ext_vector_type(4)));

#define KC 4        // k-chunks of 32: k=0..99 real, k=100 -> t, k=101 -> 1
#define HSTRIDE 104 // halves per comb row (208 B, 16B-aligned)

// v2: 4 waves per tree, nt-split. Wave w owns output-feature tiles
// nt in {w, w+4} (wave 3: {3} only). 256-thread blocks, 1024 blocks ->
// 16 waves/CU = 4 waves/SIMD (vs 1 before): per-wave serial MFMA count
// drops 980 -> ~280 AND the SIMD gets 4 streams to hide MFMA/LDS latency.
//
// LDS (40448 B total -> 4 blocks/CU exactly):
//   Abuf: 128 comb rows. Cols 100..103 of each row hold the heap t-values
//         (511 f16) -- those cols are never read/written by tile code.
//   Bbuf: 64 comb rows. First 512 halves overlay the leaf-pair t's (dead
//         before B's first real write at level 7).
//   trash: 512 B sink for nt==6,kg!=0 lanes (features >= 100).
// Ping-pong A->B->A.. per level with ONE __syncthreads per level; the
// nt-split makes every wave read every tile's rows, so in-place halving
// would race across waves -- disjoint src/dst buffers are required.
// Odd sibling lanes hold identical post-DPP sums as their even partner and
// store to the SAME address (benign, 2-way same-addr = free) -- no trash
// detour, no exec masking.
__global__ __launch_bounds__(256, 4)
void grnn_fused(const float* __restrict__ times,
                const float* __restrict__ Qw,
                const float* __restrict__ Qb,
                const float* __restrict__ Ww,
                const float* __restrict__ Wb,
                const float* __restrict__ Pw,
                const float* __restrict__ Pb,
                float* __restrict__ out)
{
  __shared__ __align__(16) _Float16 Abuf[128 * HSTRIDE]; // 26624 B
  __shared__ __align__(16) _Float16 Bbuf[64 * HSTRIDE];  // 13312 B
  __shared__ __align__(16) _Float16 trash[256];          //   512 B

  const int tid  = threadIdx.x;        // 0..255
  const int lane = tid & 63;
  const int w    = tid >> 6;           // wave id 0..3
  const int l15  = lane & 15;
  const int kg   = lane >> 4;
  const int tree = blockIdx.x;
  const bool two = (w < 3);            // wave owns 2 nt values (else 1)

  _Float16* const Af = Abuf;
  _Float16* const Bf = Bbuf;

  // ---- stage times: heap t -> A cols 100..103; leaf pairs -> B overlay ----
  {
    const float* tg = times + tree * 1023;
    Af[(tid >> 2) * HSTRIDE + 100 + (tid & 3)] = (_Float16)tg[tid];
    if (tid < 255) {
      const int i = tid + 256;
      Af[(i >> 2) * HSTRIDE + 100 + (i & 3)] = (_Float16)tg[i];
    }
    ((h2*)Bf)[tid] = (h2){(_Float16)tg[511 + 2 * tid], (_Float16)tg[512 + 2 * tid]};
  }

  // ---- per-wave W fragments for its nt set (B[k][n]=Ww[n][k]); fold rows
  //      k=100 -> Qw, k=101 -> Qb+Wb. wave 3, s=1 -> nt=7 -> all zero.
  h8 wf[2][KC];
  #pragma unroll
  for (int s = 0; s < 2; ++s) {
    const int nt = w + 4 * s;
    const int r = nt * 16 + l15;       // >=100 for nt==7 -> stays zero
    #pragma unroll
    for (int kc = 0; kc < KC; ++kc) {
      h8 v;
      #pragma unroll
      for (int j = 0; j < 8; ++j) v[j] = (_Float16)0.f;
      if (r < 100) {
        const int kb = kc * 32 + kg * 8;
        if (kc < 3) {
          const f4 w0 = *(const f4*)&Ww[r * 100 + kb];
          const f4 w1 = *(const f4*)&Ww[r * 100 + kb + 4];
          #pragma unroll
          for (int j = 0; j < 4; ++j) {
            v[j]     = (_Float16)w0[j];
            v[j + 4] = (_Float16)w1[j];
          }
        } else if (kg == 0) {
          const f4 w0 = *(const f4*)&Ww[r * 100 + 96];
          #pragma unroll
          for (int j = 0; j < 4; ++j) v[j] = (_Float16)w0[j];
          v[4] = (_Float16)Qw[r];            // k=100
          v[5] = (_Float16)(Qb[r] + Wb[r]);  // k=101
        }
      }
      wf[s][kc] = v;
    }
  }

  // ---- packed leaf Q vectors (features kb..kb+7 per lane, f16) ----
  h8 qwp[KC], qbp[KC];
  #pragma unroll
  for (int kc = 0; kc < KC; ++kc) {
    const int kb = kc * 32 + kg * 8;
    #pragma unroll
    for (int j = 0; j < 8; ++j) {
      const int ix = kb + j;
      qwp[kc][j] = (ix < 100) ? (_Float16)Qw[ix] : (_Float16)0.f;
      qbp[kc][j] = (ix < 100) ? (_Float16)Qb[ix] : (_Float16)0.f;
    }
  }

  __syncthreads();   // staged t's visible to all waves

// MFMA tile + epilogue for the wave's nt set. Lane(l15,kg) reg r = feature
// nt*16+kg*4+r of node MT*16+l15. cvt->relu -> DPP quad_perm(1,0,3,2)
// sibling add (both lanes of a pair end with the sum; both store the same
// address -- same data, benign). nt==6,kg!=0 lanes (features>=100) -> trash.
#define DO_MT(AFR, DSTP, MT) do {                                             \
    _Float16* pv_ = (DSTP) + ((MT) * 8 + (l15 >> 1)) * HSTRIDE + kg * 4;      \
    _Pragma("unroll")                                                         \
    for (int s_ = 0; s_ < 2; ++s_) {                                          \
      if (s_ && !two) break;                                                  \
      const int nt_ = w + 4 * s_;                                             \
      f4 acc_ = {0.f, 0.f, 0.f, 0.f};                                         \
      _Pragma("unroll")                                                       \
      for (int kc_ = 0; kc_ < KC; ++kc_)                                      \
        acc_ = __builtin_amdgcn_mfma_f32_16x16x32_f16(wf[s_][kc_],            \
                                                      AFR[kc_], acc_, 0,0,0); \
      h2 c0_ = {(_Float16)acc_[0], (_Float16)acc_[1]};                        \
      h2 c1_ = {(_Float16)acc_[2], (_Float16)acc_[3]};                        \
      const h2 z2_ = {(_Float16)0.f, (_Float16)0.f};                          \
      c0_ = __builtin_elementwise_max(c0_, z2_);                              \
      c1_ = __builtin_elementwise_max(c1_, z2_);                              \
      int d0_ = __builtin_amdgcn_mov_dpp(__builtin_bit_cast(int, c0_),        \
                                         0xB1, 0xF, 0xF, true);               \
      int d1_ = __builtin_amdgcn_mov_dpp(__builtin_bit_cast(int, c1_),        \
                                         0xB1, 0xF, 0xF, true);               \
      c0_ = c0_ + __builtin_bit_cast(h2, d0_);                                \
      c1_ = c1_ + __builtin_bit_cast(h2, d1_);                                \
      h4 hv_ = {c0_[0], c0_[1], c1_[0], c1_[1]};                              \
      _Float16* p_ = ((nt_ == 6) & (kg != 0)) ? &trash[lane * 4]              \
                                              : pv_ + nt_ * 16;               \
      *(h4*)p_ = hv_;                                                         \
    }                                                                         \
  } while (0)

// Root: no sibling add; only l15==0 (node 0) stores its nt cols into A row 0.
#define DO_MT_ROOT(AFR) do {                                                  \
    _Pragma("unroll")                                                         \
    for (int s_ = 0; s_ < 2; ++s_) {                                          \
      if (s_ && !two) break;                                                  \
      const int nt_ = w + 4 * s_;                                             \
      f4 acc_ = {0.f, 0.f, 0.f, 0.f};                                         \
      _Pragma("unroll")                                                       \
      for (int kc_ = 0; kc_ < KC; ++kc_)                                      \
        acc_ = __builtin_amdgcn_mfma_f32_16x16x32_f16(wf[s_][kc_],            \
                                                      AFR[kc_], acc_, 0,0,0); \
      h2 c0_ = {(_Float16)acc_[0], (_Float16)acc_[1]};                        \
      h2 c1_ = {(_Float16)acc_[2], (_Float16)acc_[3]};                        \
      const h2 z2_ = {(_Float16)0.f, (_Float16)0.f};                          \
      c0_ = __builtin_elementwise_max(c0_, z2_);                              \
      c1_ = __builtin_elementwise_max(c1_, z2_);                              \
      h4 hv_ = {c0_[0], c0_[1], c1_[0], c1_[1]};                              \
      _Float16* p_ = ((l15 == 0) & !((nt_ == 6) & (kg != 0)))                 \
                         ? Af + nt_ * 16 + kg * 4 : &trash[lane * 4];         \
      *(h4*)p_ = hv_;                                                         \
    }                                                                         \
  } while (0)

// Load A-fragment for tile MT from SRCP; t (heap base S) from A cols 100+.
#define LOAD_AFR(AFR, SRCP, MT, S) do {                                       \
    const int rb_ = ((MT) * 16 + l15) * HSTRIDE;                              \
    AFR[0] = *(const h8*)((SRCP) + rb_ + kg * 8);                             \
    AFR[1] = *(const h8*)((SRCP) + rb_ + 32 + kg * 8);                        \
    AFR[2] = *(const h8*)((SRCP) + rb_ + 64 + kg * 8);                        \
    h4 lo_ = *(const h4*)((SRCP) + rb_ + 96);                                 \
    const int ti_ = (S) + (MT) * 16 + l15;                                    \
    h4 hi_ = {Af[(ti_ >> 2) * HSTRIDE + 100 + (ti_ & 3)], (_Float16)1.f,      \
              (_Float16)0.f, (_Float16)0.f};                                  \
    AFR[3] = __builtin_shufflevector(lo_, hi_, 0, 1, 2, 3, 4, 5, 6, 7);       \
  } while (0)

  // ---- level 8 (256 nodes): packed-f16 leaf comb in VALU; 16 tiles ----
  // Every wave computes every tile's A-fragment (duplicated VALU, ~cheap)
  // but MFMAs only its own nt slice. Writes A rows 0..127 (cols<=99 only).
  {
    const h8 z8 = {(_Float16)0.f, (_Float16)0.f, (_Float16)0.f, (_Float16)0.f,
                   (_Float16)0.f, (_Float16)0.f, (_Float16)0.f, (_Float16)0.f};
    const h2* tsp = (const h2*)Bf;
    #pragma unroll 2
    for (int i = 0; i < 16; ++i) {
      const int m = i * 16 + l15;
      const h2 tp = tsp[m];
      const _Float16 t0 = tp[0], t1 = tp[1];
      h8 afl[KC];
      #pragma unroll
      for (int kc = 0; kc < KC; ++kc) {
        h8 a = qwp[kc] * t0 + qbp[kc];
        h8 b = qwp[kc] * t1 + qbp[kc];
        a = __builtin_elementwise_max(a, z8);
        b = __builtin_elementwise_max(b, z8);
        afl[kc] = a + b;                 // leaf comb (features >=100 are 0)
      }
      const int ti = 255 + m;
      afl[3][4] = Af[(ti >> 2) * HSTRIDE + 100 + (ti & 3)]; // fold t
      afl[3][5] = (_Float16)1.f;
      DO_MT(afl, Af, i);
    }
  }
  __syncthreads();

  h8 af[KC], afn[KC];

  // ---- level 7: A(128 rows) -> B(64), 8 tiles, prefetch within level ----
  LOAD_AFR(af, Af, 0, 127);
  #pragma unroll 1
  for (int i = 0; i < 8; ++i) {
    if (i < 7) LOAD_AFR(afn, Af, i + 1, 127);
    DO_MT(af, Bf, i);
    #pragma unroll
    for (int c = 0; c < KC; ++c) af[c] = afn[c];
  }
  __syncthreads();

  // ---- level 6: B -> A(32), 4 tiles ----
  LOAD_AFR(af, Bf, 0, 63);
  #pragma unroll 1
  for (int i = 0; i < 4; ++i) {
    if (i < 3) LOAD_AFR(afn, Bf, i + 1, 63);
    DO_MT(af, Af, i);
    #pragma unroll
    for (int c = 0; c < KC; ++c) af[c] = afn[c];
  }
  __syncthreads();

  // ---- level 5: A -> B(16), 2 tiles ----
  LOAD_AFR(af, Af, 0, 31);
  #pragma unroll 1
  for (int i = 0; i < 2; ++i) {
    if (i < 1) LOAD_AFR(afn, Af, 1, 31);
    DO_MT(af, Bf, i);
    #pragma unroll
    for (int c = 0; c < KC; ++c) af[c] = afn[c];
  }
  __syncthreads();

  // ---- levels 4..1: single tile, ping-pong; rows beyond the level's real
  //      node count are stale-but-finite garbage feeding garbage rows ----
  #pragma unroll 1
  for (int d = 4; d >= 1; --d) {
    _Float16* const srcp = (d & 1) ? Af : Bf;
    _Float16* const dstp = (d & 1) ? Bf : Af;
    LOAD_AFR(af, srcp, 0, (1 << d) - 1);
    DO_MT(af, dstp, 0);
    __syncthreads();
  }

  // ---- root: reads B row 0, h_root -> A row 0 (cols 0..99) ----
  LOAD_AFR(af, Bf, 0, 0);
  DO_MT_ROOT(af);
  __syncthreads();

  // ---- projection: out[p] = root . Pw[p] + Pb[p]; wave w -> p in {w,w+4} ----
  #pragma unroll 1
  for (int p = w; p < 5; p += 4) {
    float v = (float)Af[lane] * Pw[p * 100 + lane];
    if (lane < 36) v += (float)Af[64 + lane] * Pw[p * 100 + 64 + lane];
    v += __shfl_xor(v, 32, 64);
    v += __shfl_xor(v, 16, 64);
    v += __shfl_xor(v, 8, 64);
    v += __shfl_xor(v, 4, 64);
    v += __shfl_xor(v, 2, 64);
    v += __shfl_xor(v, 1, 64);
    if (lane == 0) out[tree * 5 + p] = v + Pb[p];
  }
#undef DO_MT
#undef DO_MT_ROOT
#undef LOAD_AFR
}

extern "C" void kernel_launch(void* const* d_in, const int* in_sizes, int n_in,
                              void* d_out, int out_size, void* d_ws, size_t ws_size,
                              hipStream_t stream) {
  (void)n_in; (void)out_size; (void)d_ws; (void)ws_size;
  const float* times = (const float*)d_in[0];
  const float* Qw = (const float*)d_in[1];
  const float* Qb = (const float*)d_in[2];
  const float* Ww = (const float*)d_in[3];
  const float* Wb = (const float*)d_in[4];
  const float* Pw = (const float*)d_in[5];
  const float* Pb = (const float*)d_in[6];
  float* outp = (float*)d_out;
  const int B = in_sizes[0] / 1023;   // trees -> one 4-wave block each
  grnn_fused<<<dim3(B), dim3(256), 0, stream>>>(times, Qw, Qb, Ww, Wb, Pw, Pb, outp);
}

// Round 2
// 92.679 us; speedup vs baseline: 1.0262x; 1.0262x over previous
//
#include <hip/hip_runtime.h>

typedef _Float16 h8 __attribute__((ext_vector_type(8)));
typedef _Float16 h4 __attribute__((ext_vector_type(4)));
typedef _Float16 h2 __attribute__((ext_vector_type(2)));
typedef float f4 __attribute__((ext_vector_type(4)));

#define NT 7        // n-tiles: 112 output features (100 real)
#define KC 4        // k-chunks of 32: k=0..99 real, k=100 -> t, k=101 -> 1
#define HSTRIDE 104 // halves per comb row (208 B, 16B-aligned)

// v3: 2 waves per tree, SUBTREE split (not nt-split). Wave w owns the whole
// subtree rooted at node 1+w: every read comes from the wave's own writes
// (heap locality), so the in-order-DS in-place comb machinery from the
// 1-wave version applies unchanged and exactly ONE __syncthreads is needed
// (h1/h2 merge before the root). Per-wave serial stream: 980 -> 560 MFMA,
// 1280 -> 640 leaf VALU ops; 2048 waves -> 2 waves/SIMD so one wave's VALU
// epilogue co-issues under the other's MFMAs.
//
// LDS 27552 B/block -> 4 blocks/CU. VGPR ~200 -> 2 waves/SIMD (consistent).
// Per-wave private Cs[w]: 64 comb rows; in-place WAR safety per level: tile
// i reads rows 16i..16i+15, writes 8i..8i+7 (never overlaps pending writes;
// same-wave DS ops complete in order). Tail levels (<=5) preload t into
// registers so the serial tail has no global-load latency.
__global__ __launch_bounds__(128, 2)
void grnn_fused(const float* __restrict__ times,
                const float* __restrict__ Qw,
                const float* __restrict__ Qb,
                const float* __restrict__ Ww,
                const float* __restrict__ Wb,
                const float* __restrict__ Pw,
                const float* __restrict__ Pb,
                float* __restrict__ out)
{
  __shared__ __align__(16) _Float16 Cs[2][64][HSTRIDE]; // 26624 B
  __shared__ __align__(16) _Float16 Hrow[2][HSTRIDE];   //   416 B h_{1+w}
  __shared__ __align__(16) _Float16 trash[256];         //   512 B sink

  const int tid  = threadIdx.x;        // 0..127
  const int lane = tid & 63;
  const int w    = tid >> 6;           // wave id 0..1 = subtree id
  const int l15  = lane & 15;
  const int kg   = lane >> 4;
  const int tree = blockIdx.x;
  const float* tg = times + tree * 1023;
  _Float16 (* const C)[HSTRIDE] = Cs[w];

  // ---- persistent W fragments (B[k][n]=Ww[n][k]); fold rows k=100 -> Qw,
  //      k=101 -> Qb+Wb. Same regs serve as MFMA A operand (layout symmetry).
  h8 wf[NT][KC];
  #pragma unroll
  for (int nt = 0; nt < NT; ++nt) {
    const int r = nt * 16 + l15;
    #pragma unroll
    for (int kc = 0; kc < KC; ++kc) {
      h8 v;
      #pragma unroll
      for (int j = 0; j < 8; ++j) v[j] = (_Float16)0.f;
      if (r < 100) {
        const int kb = kc * 32 + kg * 8;
        if (kc < 3) {
          const f4 w0 = *(const f4*)&Ww[r * 100 + kb];
          const f4 w1 = *(const f4*)&Ww[r * 100 + kb + 4];
          #pragma unroll
          for (int j = 0; j < 4; ++j) {
            v[j]     = (_Float16)w0[j];
            v[j + 4] = (_Float16)w1[j];
          }
        } else if (kg == 0) {
          const f4 w0 = *(const f4*)&Ww[r * 100 + 96];
          #pragma unroll
          for (int j = 0; j < 4; ++j) v[j] = (_Float16)w0[j];
          v[4] = (_Float16)Qw[r];            // k=100
          v[5] = (_Float16)(Qb[r] + Wb[r]);  // k=101
        }
      }
      wf[nt][kc] = v;
    }
  }

  // ---- packed leaf Q vectors (features kb..kb+7 per lane, f16) ----
  h8 qwp[KC], qbp[KC];
  #pragma unroll
  for (int kc = 0; kc < KC; ++kc) {
    const int kb = kc * 32 + kg * 8;
    #pragma unroll
    for (int j = 0; j < 8; ++j) {
      const int ix = kb + j;
      qwp[kc][j] = (ix < 100) ? (_Float16)Qw[ix] : (_Float16)0.f;
      qbp[kc][j] = (ix < 100) ? (_Float16)Qb[ix] : (_Float16)0.f;
    }
  }

  // ---- tail-level t preloads (strip global latency off the serial tail) ----
  const _Float16 t_l5 = (_Float16)tg[31 + 16 * w + l15];
  const _Float16 t_l4 = (_Float16)tg[15 + 8 * w + l15];
  const _Float16 t_l3 = (_Float16)tg[7 + 4 * w + l15];
  const _Float16 t_l2 = (_Float16)tg[3 + 2 * w + l15];
  const _Float16 t_l1 = (_Float16)tg[1 + w + l15];  // only l15==0 col valid
  const _Float16 t_rt = (_Float16)tg[l15];          // root; only l15==0 valid

// MFMA tile + epilogue into the wave's private comb buffer. Lane(l15,kg)
// reg r = feature nt*16+kg*4+r of node MT*16+l15. cvt->relu -> DPP
// quad_perm(1,0,3,2) sibling add (lane^1 == node^1, pure VALU); both lanes
// of a pair store the same row+col (identical data -> benign). nt==6,kg!=0
// lanes (features >= 100) -> trash.
#define DO_MT(AFR, MT) do {                                                   \
    _Float16* pv_ = &C[(MT) * 8 + (l15 >> 1)][kg * 4];                        \
    _Pragma("unroll")                                                         \
    for (int nt_ = 0; nt_ < NT; ++nt_) {                                      \
      f4 acc_ = {0.f, 0.f, 0.f, 0.f};                                         \
      _Pragma("unroll")                                                       \
      for (int kc_ = 0; kc_ < KC; ++kc_)                                      \
        acc_ = __builtin_amdgcn_mfma_f32_16x16x32_f16(wf[nt_][kc_],           \
                                                      AFR[kc_], acc_, 0,0,0); \
      h2 c0_ = {(_Float16)acc_[0], (_Float16)acc_[1]};                        \
      h2 c1_ = {(_Float16)acc_[2], (_Float16)acc_[3]};                        \
      const h2 z2_ = {(_Float16)0.f, (_Float16)0.f};                          \
      c0_ = __builtin_elementwise_max(c0_, z2_);                              \
      c1_ = __builtin_elementwise_max(c1_, z2_);                              \
      int d0_ = __builtin_amdgcn_mov_dpp(__builtin_bit_cast(int, c0_),        \
                                         0xB1, 0xF, 0xF, true);               \
      int d1_ = __builtin_amdgcn_mov_dpp(__builtin_bit_cast(int, c1_),        \
                                         0xB1, 0xF, 0xF, true);               \
      c0_ = c0_ + __builtin_bit_cast(h2, d0_);                                \
      c1_ = c1_ + __builtin_bit_cast(h2, d1_);                                \
      h4 hv_ = {c0_[0], c0_[1], c1_[0], c1_[1]};                              \
      _Float16* p_ = ((nt_ == 6) & (kg != 0)) ? &trash[lane * 4]              \
                                              : pv_ + nt_ * 16;               \
      *(h4*)p_ = hv_;                                                         \
    }                                                                         \
  } while (0)

// Raw h store (no sibling add): l15==0 (node col 0) stores into DST row.
#define DO_RAW(AFR, DST) do {                                                 \
    _Pragma("unroll")                                                         \
    for (int nt_ = 0; nt_ < NT; ++nt_) {                                      \
      f4 acc_ = {0.f, 0.f, 0.f, 0.f};                                         \
      _Pragma("unroll")                                                       \
      for (int kc_ = 0; kc_ < KC; ++kc_)                                      \
        acc_ = __builtin_amdgcn_mfma_f32_16x16x32_f16(wf[nt_][kc_],           \
                                                      AFR[kc_], acc_, 0,0,0); \
      h2 c0_ = {(_Float16)acc_[0], (_Float16)acc_[1]};                        \
      h2 c1_ = {(_Float16)acc_[2], (_Float16)acc_[3]};                        \
      const h2 z2_ = {(_Float16)0.f, (_Float16)0.f};                          \
      c0_ = __builtin_elementwise_max(c0_, z2_);                              \
      c1_ = __builtin_elementwise_max(c1_, z2_);                              \
      h4 hv_ = {c0_[0], c0_[1], c1_[0], c1_[1]};                              \
      _Float16* p_ = ((l15 == 0) & !((nt_ == 6) & (kg != 0)))                 \
                         ? (DST) + nt_ * 16 + kg * 4 : &trash[lane * 4];      \
      *(h4*)p_ = hv_;                                                         \
    }                                                                         \
  } while (0)

// Load A-fragment for tile MT from the wave's comb rows; t from global.
#define LOAD_AFR(AFR, MT, TBASE) do {                                         \
    const int rr_ = (MT) * 16 + l15;                                          \
    AFR[0] = *(const h8*)&C[rr_][kg * 8];                                     \
    AFR[1] = *(const h8*)&C[rr_][32 + kg * 8];                                \
    AFR[2] = *(const h8*)&C[rr_][64 + kg * 8];                                \
    h4 lo_ = *(const h4*)&C[rr_][96];                                         \
    h4 hi_ = {(_Float16)tg[(TBASE) + (MT) * 16 + l15], (_Float16)1.f,         \
              (_Float16)0.f, (_Float16)0.f};                                  \
    AFR[3] = __builtin_shufflevector(lo_, hi_, 0, 1, 2, 3, 4, 5, 6, 7);       \
  } while (0)

// Tail variant: t already in a register.
#define LOAD_AFR_R(AFR, MT, TREG) do {                                        \
    const int rr_ = (MT) * 16 + l15;                                          \
    AFR[0] = *(const h8*)&C[rr_][kg * 8];                                     \
    AFR[1] = *(const h8*)&C[rr_][32 + kg * 8];                                \
    AFR[2] = *(const h8*)&C[rr_][64 + kg * 8];                                \
    h4 lo_ = *(const h4*)&C[rr_][96];                                         \
    h4 hi_ = {(TREG), (_Float16)1.f, (_Float16)0.f, (_Float16)0.f};           \
    AFR[3] = __builtin_shufflevector(lo_, hi_, 0, 1, 2, 3, 4, 5, 6, 7);       \
  } while (0)

  // ---- leaf phase: 128 leaf pairs -> 8 MFMA tiles (the wave's 128 L8
  //      nodes); leaf-pair combs computed in packed-f16 VALU directly as
  //      A-fragments; writes comb rows 0..63 ----
  {
    const h8 z8 = {(_Float16)0.f, (_Float16)0.f, (_Float16)0.f, (_Float16)0.f,
                   (_Float16)0.f, (_Float16)0.f, (_Float16)0.f, (_Float16)0.f};
    const int lb = 511 + 256 * w;    // wave's first leaf
    const int nb = 255 + 128 * w;    // wave's first L8 node
    #pragma unroll 2
    for (int i = 0; i < 8; ++i) {
      const int m = i * 16 + l15;    // pair index within subtree
      const _Float16 t0 = (_Float16)tg[lb + 2 * m];
      const _Float16 t1 = (_Float16)tg[lb + 2 * m + 1];
      h8 afl[KC];
      #pragma unroll
      for (int kc = 0; kc < KC; ++kc) {
        h8 a = qwp[kc] * t0 + qbp[kc];
        h8 b = qwp[kc] * t1 + qbp[kc];
        a = __builtin_elementwise_max(a, z8);
        b = __builtin_elementwise_max(b, z8);
        afl[kc] = a + b;                 // leaf comb (features >=100 are 0)
      }
      afl[3][4] = (_Float16)tg[nb + m];  // fold t of the L8 node
      afl[3][5] = (_Float16)1.f;
      DO_MT(afl, i);
    }
  }

  // ---- L7 (4 tiles) + L6 (2 tiles): early-prefetch pipeline.
  //      Prefetch reads never overlap pending writes: L6t0 reads rows 0..15
  //      (done by L7t0/t1) while L7t3 writes 24..31. ----
  h8 af[KC], afn[KC];
  const int b7 = 127 + 64 * w;
  const int b6 = 63 + 32 * w;
  LOAD_AFR(af, 0, b7);
  #pragma unroll 1
  for (int j = 0; j < 6; ++j) {
    const int i = (j < 4) ? j : j - 4;
    if (j < 5) {
      const int j2 = j + 1;
      const int i2 = (j2 < 4) ? j2 : j2 - 4;
      LOAD_AFR(afn, i2, (j2 < 4) ? b7 : b6);
    }
    DO_MT(af, i);
    #pragma unroll
    for (int c = 0; c < KC; ++c) af[c] = afn[c];
  }

  // ---- tail L5..L2: single tile each, load-after-store (in-order DS);
  //      rows beyond the level's valid node count are stale-but-finite ----
  LOAD_AFR_R(af, 0, t_l5); DO_MT(af, 0);
  LOAD_AFR_R(af, 0, t_l4); DO_MT(af, 0);
  LOAD_AFR_R(af, 0, t_l3); DO_MT(af, 0);
  LOAD_AFR_R(af, 0, t_l2); DO_MT(af, 0);

  // ---- L1: h_{1+w} raw (sibling lives in the other wave) -> Hrow[w] ----
  LOAD_AFR_R(af, 0, t_l1);
  DO_RAW(af, &Hrow[w][0]);

  __syncthreads();   // the ONE cross-wave exchange

  // ---- root: comb = h1 + h2 (all lanes use col-0 data; extra cols are
  //      redundant copies, harmless). Both waves compute the root
  //      redundantly into their private C[0] -> no further sync. ----
  {
    af[0] = *(const h8*)&Hrow[0][kg * 8]  + *(const h8*)&Hrow[1][kg * 8];
    af[1] = *(const h8*)&Hrow[0][32 + kg * 8] + *(const h8*)&Hrow[1][32 + kg * 8];
    af[2] = *(const h8*)&Hrow[0][64 + kg * 8] + *(const h8*)&Hrow[1][64 + kg * 8];
    h4 lo0 = *(const h4*)&Hrow[0][96];
    h4 lo1 = *(const h4*)&Hrow[1][96];
    h4 lo = lo0 + lo1;
    h4 hi = {t_rt, (_Float16)1.f, (_Float16)0.f, (_Float16)0.f};
    af[3] = __builtin_shufflevector(lo, hi, 0, 1, 2, 3, 4, 5, 6, 7);
  }
  DO_RAW(af, &C[0][0]);

  // ---- projection: out[p] = root . Pw[p] + Pb[p]; wave w -> p = w, w+2.. ----
  #pragma unroll 1
  for (int p = w; p < 5; p += 2) {
    float v = (float)C[0][lane] * Pw[p * 100 + lane];
    if (lane < 36) v += (float)C[0][64 + lane] * Pw[p * 100 + 64 + lane];
    v += __shfl_xor(v, 32, 64);
    v += __shfl_xor(v, 16, 64);
    v += __shfl_xor(v, 8, 64);
    v += __shfl_xor(v, 4, 64);
    v += __shfl_xor(v, 2, 64);
    v += __shfl_xor(v, 1, 64);
    if (lane == 0) out[tree * 5 + p] = v + Pb[p];
  }
#undef DO_MT
#undef DO_RAW
#undef LOAD_AFR
#undef LOAD_AFR_R
}

extern "C" void kernel_launch(void* const* d_in, const int* in_sizes, int n_in,
                              void* d_out, int out_size, void* d_ws, size_t ws_size,
                              hipStream_t stream) {
  (void)n_in; (void)out_size; (void)d_ws; (void)ws_size;
  const float* times = (const float*)d_in[0];
  const float* Qw = (const float*)d_in[1];
  const float* Qb = (const float*)d_in[2];
  const float* Ww = (const float*)d_in[3];
  const float* Wb = (const float*)d_in[4];
  const float* Pw = (const float*)d_in[5];
  const float* Pb = (const float*)d_in[6];
  float* outp = (float*)d_out;
  const int B = in_sizes[0] / 1023;   // trees -> one 2-wave block each
  grnn_fused<<<dim3(B), dim3(128), 0, stream>>>(times, Qw, Qb, Ww, Wb, Pw, Pb, outp);
}